// Round 3
// 113.046 us; speedup vs baseline: 1.1836x; 1.1836x over previous
//
#include <hip/hip_runtime.h>

// Inputs/outputs are fp32 STORAGE (values bf16-quantized by the harness).
// Proven in R2: the fp32 instantiation passed (absmax = 1 output ulp).

#define HW_ 65536

// device-global scratch — rewritten fully every call; cross-kernel
// visibility via kernel-boundary ordering (R2-proven).
__device__ double g_part[128];
__device__ double g_WgP[32];
__device__ double g_bgP[8];
__device__ __align__(16) float g_Wm[8192];   // [b*8+gr][o][j] collapsed 64x4 weights
__device__ __align__(16) float g_Bm[2048];   // [b*8+gr][o]    collapsed bias

typedef float f4v __attribute__((ext_vector_type(4)));

// ---------------------------------------------------------------------------
// K1: per-(b,ch) plane sums of raw inputs (fp64). 16 planes x 8 chunks.
// ---------------------------------------------------------------------------
__global__ void k_sum(const float* __restrict__ rgb, const float* __restrict__ edge) {
    int plane = blockIdx.x;              // b*4 + ch (ch 3 == edge)
    int chunk = blockIdx.y;              // 0..7
    int b = plane >> 2, ch = plane & 3;
    const float* src = (ch < 3) ? rgb + (size_t)(b * 3 + ch) * HW_
                                : edge + (size_t)b * HW_;
    src += chunk * 8192;
    int t = threadIdx.x;
    double s = 0.0;
    #pragma unroll
    for (int p = 0; p < 8; ++p) {
        float4 v = *(const float4*)(src + (p * 256 + t) * 4);
        s += (double)v.x + (double)v.y + (double)v.z + (double)v.w;
    }
    #pragma unroll
    for (int off = 32; off; off >>= 1) s += __shfl_down(s, off);
    __shared__ double wsum[4];
    if ((t & 63) == 0) wsum[t >> 6] = s;
    __syncthreads();
    if (t == 0) g_part[plane * 8 + chunk] = wsum[0] + wsum[1] + wsum[2] + wsum[3];
}

// ---------------------------------------------------------------------------
// K2: fused params. grid 32 = b*8+gr, 256 threads.
//  - per-block (redundant, cheap): means -> g[b][.] -> t = sigmoid(.) (8 vals)
//  - block 0 extra: collapsed guide weights WgP/bgP (fp64)
//  - collapse kernel -> 64x4 weights + bias, c-loop split 4-way across threads
//    (t = cq*64 + o), LDS fp64 reduce. Chain length / 4 vs previous k_params_b.
// ---------------------------------------------------------------------------
__global__ void k_params(const float* __restrict__ W1, const float* __restrict__ b1,
                         const float* __restrict__ Wk1, const float* __restrict__ bk1,
                         const float* __restrict__ Wk2, const float* __restrict__ bk2,
                         const float* __restrict__ Wg, const float* __restrict__ bg) {
    int blk = blockIdx.x;          // b*8 + gr
    int b = blk >> 3, gr = blk & 7;
    int t = threadIdx.x;           // 0..255
    __shared__ double xm[16];
    __shared__ double gsh[64];
    __shared__ double tt_sh[8];
    __shared__ double red[4][64][5];   // cq partials: aw0..aw3, ab

    if (t < 16) {
        double s = 0;
        #pragma unroll
        for (int i = 0; i < 8; ++i) s += g_part[t * 8 + i];
        xm[t] = s * (1.0 / 65536.0);
    }
    __syncthreads();
    if (t < 64) {   // g[b][c] for own b only
        double acc = (double)b1[t];
        #pragma unroll
        for (int j = 0; j < 4; ++j) acc += (double)W1[t * 4 + j] * xm[b * 4 + j];
        gsh[t] = acc;
    }
    __syncthreads();
    if (t < 8) {    // t-values for own (b, gr) only: j = gr*8 + i
        int j = gr * 8 + t;
        double z = (double)bk1[j];
        for (int c = 0; c < 64; ++c) z += (double)Wk1[j * 64 + c] * gsh[c];
        tt_sh[t] = 1.0 / (1.0 + exp(-z));
    }
    if (blk == 0) {  // collapsed guide weights, once globally
        if (t >= 64 && t < 96) {
            int r = (t - 64) >> 2, j = (t - 64) & 3;
            double a = 0;
            for (int c = 0; c < 64; ++c)
                a += (double)Wg[r * 64 + c] * (double)W1[c * 4 + j];
            g_WgP[t - 64] = a;
        } else if (t >= 96 && t < 104) {
            int r = t - 96;
            double a = (double)bg[r];
            for (int c = 0; c < 64; ++c)
                a += (double)Wg[r * 64 + c] * (double)b1[c];
            g_bgP[r] = a;
        }
    }
    __syncthreads();

    int o = t & 63, cq = t >> 6;
    double tt[8];
    #pragma unroll
    for (int i = 0; i < 8; ++i) tt[i] = tt_sh[i];
    double aw0 = 0, aw1 = 0, aw2 = 0, aw3 = 0, ab = 0;
    const float* wk2p = Wk2 + ((size_t)gr * 4096 + o * 64) * 8;
    const float* bk2p = bk2 + (size_t)gr * 4096 + o * 64;
    for (int c = cq * 16; c < cq * 16 + 16; ++c) {
        double ker = (double)bk2p[c];
        #pragma unroll
        for (int i = 0; i < 8; ++i)
            ker += tt[i] * (double)wk2p[c * 8 + i];
        aw0 += ker * (double)W1[c * 4 + 0];
        aw1 += ker * (double)W1[c * 4 + 1];
        aw2 += ker * (double)W1[c * 4 + 2];
        ab  += ker * (double)b1[c];
        aw3 += ker * (double)W1[c * 4 + 3];
    }
    red[cq][o][0] = aw0; red[cq][o][1] = aw1; red[cq][o][2] = aw2;
    red[cq][o][3] = aw3; red[cq][o][4] = ab;
    __syncthreads();
    if (t < 64) {
        double w0 = 0, w1 = 0, w2 = 0, w3 = 0, bb = 0;
        #pragma unroll
        for (int q = 0; q < 4; ++q) {
            w0 += red[q][t][0]; w1 += red[q][t][1]; w2 += red[q][t][2];
            w3 += red[q][t][3]; bb += red[q][t][4];
        }
        float* w = g_Wm + ((size_t)blk * 64 + t) * 4;
        w[0] = (float)w0; w[1] = (float)w1; w[2] = (float)w2; w[3] = (float)w3;
        g_Bm[blk * 64 + t] = (float)bb;
    }
}

// ---------------------------------------------------------------------------
// K3: per-pixel guide argmax + collapsed 64x4 matvec.
// Channel-split 4-way across blockIdx.z -> 1024 blocks = 4 blocks/CU
// (was 256 = 1 block/CU, 1 wave/SIMD — grid-starved). Each block handles
// output channels [z*16, z*16+16). Inputs re-read per z (L2-resident).
// LDS: W stride 68 floats -> region r base bank 4r; bias stride 20 ->
// banks {0,20,8,28,16,4,24,12}; both conflict-free for 8-way region
// divergence, both 16B-aligned per region.
// ---------------------------------------------------------------------------
__launch_bounds__(256)
__global__ void k_main(const float* __restrict__ rgb, const float* __restrict__ edge,
                       float* __restrict__ out) {
    __shared__ __align__(16) float sW[8 * 68];
    __shared__ __align__(16) float sB[8 * 20];
    __shared__ double sWg[32];
    __shared__ double sBg[8];
    int t = threadIdx.x;
    int b = blockIdx.y;
    int z = blockIdx.z;            // channel quarter

    {   // stage this (batch, channel-quarter)'s collapsed kernels
        if (t < 128) {
            int r = t >> 4, ol = t & 15;
            const float4* src = (const float4*)g_Wm;
            *(float4*)&sW[r * 68 + ol * 4] = src[(size_t)(b * 8 + r) * 64 + z * 16 + ol];
        } else {
            int idx = t - 128;
            int r = idx >> 4, ol = idx & 15;
            sB[r * 20 + ol] = g_Bm[(size_t)(b * 8 + r) * 64 + z * 16 + ol];
        }
        if (t < 32) sWg[t] = g_WgP[t];
        else if (t < 40) sBg[t - 32] = g_bgP[t - 32];
    }
    __syncthreads();

    // guide weights in registers (fully unrolled -> VGPRs)
    float wg[32], bgf[8];
    #pragma unroll
    for (int i = 0; i < 32; ++i) wg[i] = (float)sWg[i];
    #pragma unroll
    for (int r = 0; r < 8; ++r) bgf[r] = (float)sBg[r];

    int pxb = (blockIdx.x * 256 + t) * 4;
    float xa[4], xb[4], xc[4], xd[4];
    {
        float4 v0 = *(const float4*)(rgb  + (size_t)(b * 3 + 0) * HW_ + pxb);
        float4 v1 = *(const float4*)(rgb  + (size_t)(b * 3 + 1) * HW_ + pxb);
        float4 v2 = *(const float4*)(rgb  + (size_t)(b * 3 + 2) * HW_ + pxb);
        float4 v3 = *(const float4*)(edge + (size_t)b * HW_ + pxb);
        xa[0] = v0.x; xa[1] = v0.y; xa[2] = v0.z; xa[3] = v0.w;
        xb[0] = v1.x; xb[1] = v1.y; xb[2] = v1.z; xb[3] = v1.w;
        xc[0] = v2.x; xc[1] = v2.y; xc[2] = v2.z; xc[3] = v2.w;
        xd[0] = v3.x; xd[1] = v3.y; xd[2] = v3.z; xd[3] = v3.w;
    }

    // region argmax: fp32 fast path, fp64 refine on near-ties (first-max wins)
    int reg[4];
    #pragma unroll
    for (int p = 0; p < 4; ++p) {
        float m1 = -1e30f, m2 = -1e30f; int bi = 0;
        #pragma unroll
        for (int r = 0; r < 8; ++r) {
            float gv = bgf[r] + wg[r * 4 + 0] * xa[p] + wg[r * 4 + 1] * xb[p]
                              + wg[r * 4 + 2] * xc[p] + wg[r * 4 + 3] * xd[p];
            if (gv > m1) { m2 = m1; m1 = gv; bi = r; }
            else if (gv > m2) { m2 = gv; }
        }
        if (m1 - m2 < 1e-4f) {
            double da = xa[p], db = xb[p], dc = xc[p], dd = xd[p];
            double bm = -1e300; bi = 0;
            #pragma unroll
            for (int r = 0; r < 8; ++r) {
                double gv = sBg[r] + sWg[r * 4 + 0] * da + sWg[r * 4 + 1] * db
                                   + sWg[r * 4 + 2] * dc + sWg[r * 4 + 3] * dd;
                if (gv > bm) { bm = gv; bi = r; }
            }
        }
        reg[p] = bi;
    }

    int base[4], bbase[4];
    #pragma unroll
    for (int p = 0; p < 4; ++p) { base[p] = reg[p] * 68; bbase[p] = reg[p] * 20; }

    float* outp = out + (size_t)(b * 64 + z * 16) * HW_ + pxb;
    #pragma unroll
    for (int oq = 0; oq < 4; ++oq) {
        float res[4][4];                       // [k within quad][px]
        #pragma unroll
        for (int p = 0; p < 4; ++p) {
            float4 bq = *(const float4*)&sB[bbase[p] + oq * 4];
            float bqa[4] = {bq.x, bq.y, bq.z, bq.w};
            #pragma unroll
            for (int k = 0; k < 4; ++k) {
                float4 w = *(const float4*)&sW[base[p] + (oq * 4 + k) * 4];
                res[k][p] = bqa[k] + w.x * xa[p] + w.y * xb[p]
                                   + w.z * xc[p] + w.w * xd[p];
            }
        }
        #pragma unroll
        for (int k = 0; k < 4; ++k) {
            // output is write-once, never re-read in-kernel -> nontemporal
            f4v pk; pk.x = res[k][0]; pk.y = res[k][1];
            pk.z = res[k][2]; pk.w = res[k][3];
            __builtin_nontemporal_store(pk, (f4v*)(outp + (size_t)(oq * 4 + k) * HW_));
        }
    }
}

// ---------------------------------------------------------------------------
extern "C" void kernel_launch(void* const* d_in, const int* in_sizes, int n_in,
                              void* d_out, int out_size, void* d_ws, size_t ws_size,
                              hipStream_t stream) {
    (void)d_ws; (void)ws_size;
    const float* rgb  = (const float*)d_in[0];
    const float* edge = (const float*)d_in[1];
    const float* W1   = (const float*)d_in[2];
    const float* b1   = (const float*)d_in[3];
    const float* Wk1  = (const float*)d_in[4];
    const float* bk1  = (const float*)d_in[5];
    const float* Wk2  = (const float*)d_in[6];
    const float* bk2  = (const float*)d_in[7];
    const float* Wg   = (const float*)d_in[8];
    const float* bg   = (const float*)d_in[9];
    float* out = (float*)d_out;

    k_sum<<<dim3(16, 8), 256, 0, stream>>>(rgb, edge);
    k_params<<<32, 256, 0, stream>>>(W1, b1, Wk1, bk1, Wk2, bk2, Wg, bg);
    k_main<<<dim3(64, 4, 4), 256, 0, stream>>>(rgb, edge, out);
}

// Round 4
// 111.221 us; speedup vs baseline: 1.2030x; 1.0164x over previous
//
#include <hip/hip_runtime.h>

// Inputs/outputs are fp32 STORAGE (values bf16-quantized by the harness).
// Proven in R2: the fp32 instantiation passed (absmax = 1 output ulp).

#define HW_ 65536

// device-global scratch — rewritten fully every call; cross-kernel
// visibility via kernel-boundary ordering (R2-proven).
__device__ double g_part[128];
__device__ double g_WgP[32];
__device__ double g_bgP[8];
__device__ float  g_WgPf[32];   // fp32 copies for the SGPR fast path
__device__ float  g_bgPf[8];
__device__ __align__(16) float g_Wm[8192];   // [b*8+gr][o][j] collapsed 64x4 weights
__device__ __align__(16) float g_Bm[2048];   // [b*8+gr][o]    collapsed bias

typedef float f4v __attribute__((ext_vector_type(4)));

// ---------------------------------------------------------------------------
// K1: per-(b,ch) plane sums of raw inputs (fp64). 16 planes x 8 chunks.
// ---------------------------------------------------------------------------
__global__ void k_sum(const float* __restrict__ rgb, const float* __restrict__ edge) {
    int plane = blockIdx.x;              // b*4 + ch (ch 3 == edge)
    int chunk = blockIdx.y;              // 0..7
    int b = plane >> 2, ch = plane & 3;
    const float* src = (ch < 3) ? rgb + (size_t)(b * 3 + ch) * HW_
                                : edge + (size_t)b * HW_;
    src += chunk * 8192;
    int t = threadIdx.x;
    double s = 0.0;
    #pragma unroll
    for (int p = 0; p < 8; ++p) {
        float4 v = *(const float4*)(src + (p * 256 + t) * 4);
        s += (double)v.x + (double)v.y + (double)v.z + (double)v.w;
    }
    #pragma unroll
    for (int off = 32; off; off >>= 1) s += __shfl_down(s, off);
    __shared__ double wsum[4];
    if ((t & 63) == 0) wsum[t >> 6] = s;
    __syncthreads();
    if (t == 0) g_part[plane * 8 + chunk] = wsum[0] + wsum[1] + wsum[2] + wsum[3];
}

// ---------------------------------------------------------------------------
// K2: fused params. grid 32 = b*8+gr, 256 threads.
//  - per-block (redundant, cheap): means -> g[b][.] -> t = sigmoid(.) (8 vals)
//  - block 0 extra: collapsed guide weights WgP/bgP (fp64 + fp32 copies)
//  - collapse kernel -> 64x4 weights + bias, c-loop split 4-way across threads
//    (t = cq*64 + o), LDS fp64 reduce.
// ---------------------------------------------------------------------------
__global__ void k_params(const float* __restrict__ W1, const float* __restrict__ b1,
                         const float* __restrict__ Wk1, const float* __restrict__ bk1,
                         const float* __restrict__ Wk2, const float* __restrict__ bk2,
                         const float* __restrict__ Wg, const float* __restrict__ bg) {
    int blk = blockIdx.x;          // b*8 + gr
    int b = blk >> 3, gr = blk & 7;
    int t = threadIdx.x;           // 0..255
    __shared__ double xm[16];
    __shared__ double gsh[64];
    __shared__ double tt_sh[8];
    __shared__ double red[4][64][5];   // cq partials: aw0..aw3, ab

    if (t < 16) {
        double s = 0;
        #pragma unroll
        for (int i = 0; i < 8; ++i) s += g_part[t * 8 + i];
        xm[t] = s * (1.0 / 65536.0);
    }
    __syncthreads();
    if (t < 64) {   // g[b][c] for own b only
        double acc = (double)b1[t];
        #pragma unroll
        for (int j = 0; j < 4; ++j) acc += (double)W1[t * 4 + j] * xm[b * 4 + j];
        gsh[t] = acc;
    }
    __syncthreads();
    if (t < 8) {    // t-values for own (b, gr) only: j = gr*8 + i
        int j = gr * 8 + t;
        double z = (double)bk1[j];
        for (int c = 0; c < 64; ++c) z += (double)Wk1[j * 64 + c] * gsh[c];
        tt_sh[t] = 1.0 / (1.0 + exp(-z));
    }
    if (blk == 0) {  // collapsed guide weights, once globally
        if (t >= 64 && t < 96) {
            int r = (t - 64) >> 2, j = (t - 64) & 3;
            double a = 0;
            for (int c = 0; c < 64; ++c)
                a += (double)Wg[r * 64 + c] * (double)W1[c * 4 + j];
            g_WgP[t - 64] = a;
            g_WgPf[t - 64] = (float)a;
        } else if (t >= 96 && t < 104) {
            int r = t - 96;
            double a = (double)bg[r];
            for (int c = 0; c < 64; ++c)
                a += (double)Wg[r * 64 + c] * (double)b1[c];
            g_bgP[r] = a;
            g_bgPf[r] = (float)a;
        }
    }
    __syncthreads();

    int o = t & 63, cq = t >> 6;
    double tt[8];
    #pragma unroll
    for (int i = 0; i < 8; ++i) tt[i] = tt_sh[i];
    double aw0 = 0, aw1 = 0, aw2 = 0, aw3 = 0, ab = 0;
    const float* wk2p = Wk2 + ((size_t)gr * 4096 + o * 64) * 8;
    const float* bk2p = bk2 + (size_t)gr * 4096 + o * 64;
    for (int c = cq * 16; c < cq * 16 + 16; ++c) {
        double ker = (double)bk2p[c];
        #pragma unroll
        for (int i = 0; i < 8; ++i)
            ker += tt[i] * (double)wk2p[c * 8 + i];
        aw0 += ker * (double)W1[c * 4 + 0];
        aw1 += ker * (double)W1[c * 4 + 1];
        aw2 += ker * (double)W1[c * 4 + 2];
        ab  += ker * (double)b1[c];
        aw3 += ker * (double)W1[c * 4 + 3];
    }
    red[cq][o][0] = aw0; red[cq][o][1] = aw1; red[cq][o][2] = aw2;
    red[cq][o][3] = aw3; red[cq][o][4] = ab;
    __syncthreads();
    if (t < 64) {
        double w0 = 0, w1 = 0, w2 = 0, w3 = 0, bb = 0;
        #pragma unroll
        for (int q = 0; q < 4; ++q) {
            w0 += red[q][t][0]; w1 += red[q][t][1]; w2 += red[q][t][2];
            w3 += red[q][t][3]; bb += red[q][t][4];
        }
        float* w = g_Wm + ((size_t)blk * 64 + t) * 4;
        w[0] = (float)w0; w[1] = (float)w1; w[2] = (float)w2; w[3] = (float)w3;
        g_Bm[blk * 64 + t] = (float)bb;
    }
}

// ---------------------------------------------------------------------------
// K3: per-pixel guide argmax + collapsed 64x4 matvec.
// Channel-split 8-way (blockIdx.z) -> 2048 blocks; __launch_bounds__(256,6)
// caps VGPR at 85 -> 6 blocks/CU (24 waves/CU, was 16). Guide weights are
// wave-uniform -> forced to SGPRs via readfirstlane (frees ~40 VGPRs).
// Input loads hoisted above LDS staging so HBM latency hides under it.
// LDS: W stride 36 floats -> region r base bank 4r; bias stride 12 ->
// banks {0,12,24,4,16,28,8,20}; conflict-free for 8-way region divergence,
// 16B-aligned per region.
// ---------------------------------------------------------------------------
__launch_bounds__(256, 6)
__global__ void k_main(const float* __restrict__ rgb, const float* __restrict__ edge,
                       float* __restrict__ out) {
    __shared__ __align__(16) float sW[8 * 36];
    __shared__ __align__(16) float sB[8 * 12];
    __shared__ double sWg[32];
    __shared__ double sBg[8];
    int t = threadIdx.x;
    int b = blockIdx.y;
    int z = blockIdx.z;            // channel octant: channels [z*8, z*8+8)

    // ---- issue input loads FIRST (latency overlaps staging + barrier) ----
    int pxb = (blockIdx.x * 256 + t) * 4;
    float4 v0 = *(const float4*)(rgb  + (size_t)(b * 3 + 0) * HW_ + pxb);
    float4 v1 = *(const float4*)(rgb  + (size_t)(b * 3 + 1) * HW_ + pxb);
    float4 v2 = *(const float4*)(rgb  + (size_t)(b * 3 + 2) * HW_ + pxb);
    float4 v3 = *(const float4*)(edge + (size_t)b * HW_ + pxb);

    {   // stage this (batch, channel-octant)'s collapsed kernels
        if (t < 64) {
            int r = t >> 3, ol = t & 7;
            const float4* src = (const float4*)g_Wm;
            *(float4*)&sW[r * 36 + ol * 4] = src[(size_t)(b * 8 + r) * 64 + z * 8 + ol];
        } else if (t < 128) {
            int idx = t - 64;
            int r = idx >> 3, ol = idx & 7;
            sB[r * 12 + ol] = g_Bm[(size_t)(b * 8 + r) * 64 + z * 8 + ol];
        } else if (t < 160) {
            sWg[t - 128] = g_WgP[t - 128];
        } else if (t < 168) {
            sBg[t - 160] = g_bgP[t - 160];
        }
    }
    __syncthreads();

    // guide weights: wave-uniform -> SGPRs (readfirstlane), zero VGPR cost
    float wg[32], bgf[8];
    #pragma unroll
    for (int i = 0; i < 32; ++i)
        wg[i] = __int_as_float(__builtin_amdgcn_readfirstlane(__float_as_int(g_WgPf[i])));
    #pragma unroll
    for (int r = 0; r < 8; ++r)
        bgf[r] = __int_as_float(__builtin_amdgcn_readfirstlane(__float_as_int(g_bgPf[r])));

    float xa[4], xb[4], xc[4], xd[4];
    xa[0] = v0.x; xa[1] = v0.y; xa[2] = v0.z; xa[3] = v0.w;
    xb[0] = v1.x; xb[1] = v1.y; xb[2] = v1.z; xb[3] = v1.w;
    xc[0] = v2.x; xc[1] = v2.y; xc[2] = v2.z; xc[3] = v2.w;
    xd[0] = v3.x; xd[1] = v3.y; xd[2] = v3.z; xd[3] = v3.w;

    // region argmax: fp32 fast path, fp64 refine on near-ties (first-max wins)
    int reg[4];
    #pragma unroll
    for (int p = 0; p < 4; ++p) {
        float m1 = -1e30f, m2 = -1e30f; int bi = 0;
        #pragma unroll
        for (int r = 0; r < 8; ++r) {
            float gv = bgf[r] + wg[r * 4 + 0] * xa[p] + wg[r * 4 + 1] * xb[p]
                              + wg[r * 4 + 2] * xc[p] + wg[r * 4 + 3] * xd[p];
            if (gv > m1) { m2 = m1; m1 = gv; bi = r; }
            else if (gv > m2) { m2 = gv; }
        }
        if (m1 - m2 < 1e-4f) {
            double da = xa[p], db = xb[p], dc = xc[p], dd = xd[p];
            double bm = -1e300; bi = 0;
            #pragma unroll
            for (int r = 0; r < 8; ++r) {
                double gv = sBg[r] + sWg[r * 4 + 0] * da + sWg[r * 4 + 1] * db
                                   + sWg[r * 4 + 2] * dc + sWg[r * 4 + 3] * dd;
                if (gv > bm) { bm = gv; bi = r; }
            }
        }
        reg[p] = bi;
    }

    int base[4], bbase[4];
    #pragma unroll
    for (int p = 0; p < 4; ++p) { base[p] = reg[p] * 36; bbase[p] = reg[p] * 12; }

    float* outp = out + (size_t)(b * 64 + z * 8) * HW_ + pxb;
    #pragma unroll
    for (int oq = 0; oq < 2; ++oq) {
        float res[4][4];                       // [k within quad][px]
        #pragma unroll
        for (int p = 0; p < 4; ++p) {
            float4 bq = *(const float4*)&sB[bbase[p] + oq * 4];
            float bqa[4] = {bq.x, bq.y, bq.z, bq.w};
            #pragma unroll
            for (int k = 0; k < 4; ++k) {
                float4 w = *(const float4*)&sW[base[p] + (oq * 4 + k) * 4];
                res[k][p] = bqa[k] + w.x * xa[p] + w.y * xb[p]
                                   + w.z * xc[p] + w.w * xd[p];
            }
        }
        #pragma unroll
        for (int k = 0; k < 4; ++k) {
            // output is write-once, never re-read in-kernel -> nontemporal
            f4v pk; pk.x = res[k][0]; pk.y = res[k][1];
            pk.z = res[k][2]; pk.w = res[k][3];
            __builtin_nontemporal_store(pk, (f4v*)(outp + (size_t)(oq * 4 + k) * HW_));
        }
    }
}

// ---------------------------------------------------------------------------
extern "C" void kernel_launch(void* const* d_in, const int* in_sizes, int n_in,
                              void* d_out, int out_size, void* d_ws, size_t ws_size,
                              hipStream_t stream) {
    (void)d_ws; (void)ws_size;
    const float* rgb  = (const float*)d_in[0];
    const float* edge = (const float*)d_in[1];
    const float* W1   = (const float*)d_in[2];
    const float* b1   = (const float*)d_in[3];
    const float* Wk1  = (const float*)d_in[4];
    const float* bk1  = (const float*)d_in[5];
    const float* Wk2  = (const float*)d_in[6];
    const float* bk2  = (const float*)d_in[7];
    const float* Wg   = (const float*)d_in[8];
    const float* bg   = (const float*)d_in[9];
    float* out = (float*)d_out;

    k_sum<<<dim3(16, 8), 256, 0, stream>>>(rgb, edge);
    k_params<<<32, 256, 0, stream>>>(W1, b1, Wk1, bk1, Wk2, bk2, Wg, bg);
    k_main<<<dim3(64, 4, 8), 256, 0, stream>>>(rgb, edge, out);
}